// Round 3
// baseline (310.010 us; speedup 1.0000x reference)
//
#include <hip/hip_runtime.h>
#include <hip/hip_cooperative_groups.h>
#include <math.h>

namespace cg = cooperative_groups;

#define D 196
#define NCH 64
#define NH 8
#define DHD 64
#define INNER 512
#define MLP 784
#define SEQ 65
#define GRID 260

struct Params {
    const float *x, *tokens, *x_pe, *conv_k, *bn_g, *bn_b, *bn_rm, *bn_rv;
    const float *fc_w1, *fc_w2, *ln1_g, *ln1_b, *ln2_g, *ln2_b;
    const float *w_qkv, *w_out, *b_out, *ff_w1, *ff_b1, *ff_w2, *ff_b2;
    float *a, *b1, *c, *qkv, *o, *x2, *tb, *out;
};

__device__ __forceinline__ float bsum(float v, float* red) {
    for (int off = 32; off > 0; off >>= 1) v += __shfl_down(v, off, 64);
    int lane = threadIdx.x & 63, wid = threadIdx.x >> 6;
    if (lane == 0) red[wid] = v;
    __syncthreads();
    float s = red[0] + red[1] + red[2] + red[3];
    __syncthreads();
    return s;
}

__global__ void __launch_bounds__(256, 1) k_fused(Params P) {
    __shared__ float smem[544];
    float* red = smem;        // [0,4)
    float* h   = smem + 4;    // [4,200)
    cg::grid_group grid = cg::this_grid();
    int b = blockIdx.x, t = threadIdx.x;

    // ================= Phase A: conv+mean | LN1+QKV | zero =================
    if (b < NCH) {
        const float* row = P.x_pe + b * D;
        float val = 0.f;
        if (t < D) {
            float km0 = P.conv_k[3], km1 = P.conv_k[4], km2 = P.conv_k[5];
            float inv = rsqrtf(P.bn_rv[0] + 1e-5f);
            float l = (t > 0) ? row[t - 1] : 0.f;
            float m = row[t];
            float r = (t < D - 1) ? row[t + 1] : 0.f;
            float conv = km0 * l + km1 * m + km2 * r;
            float bn = (conv - P.bn_rm[0]) * inv * P.bn_g[0] + P.bn_b[0];
            val = fmaxf(bn, 0.f);
            P.a[b * D + t] = val;
        }
        float tot = bsum(val, red);
        if (t == 0) P.b1[b] = tot * (1.f / (float)D);
    } else if (b < 259) {
        int qb = b - NCH;
        int n = qb / 3, ck = qb % 3;
        const float* row = P.x + n * D;
        float v = (t < D) ? row[t] : 0.f;
        float mean = bsum(v, red) * (1.f / (float)D);
        float d = (t < D) ? (v - mean) : 0.f;
        float var = bsum(d * d, red) * (1.f / (float)D);
        float rinv = rsqrtf(var + 1e-5f);
        if (t < D) h[t] = d * rinv * P.ln1_g[t] + P.ln1_b[t];
        __syncthreads();
        int col0 = ck * 512 + t;
        const float* w0 = P.w_qkv + col0;
        const float* w1 = P.w_qkv + col0 + 256;
        float a0 = 0.f, a1 = 0.f;
#pragma unroll 4
        for (int i = 0; i < D; i++) {
            float hv = h[i];
            a0 += hv * w0[i * 1536];
            a1 += hv * w1[i * 1536];
        }
        P.qkv[n * 1536 + col0] = a0;
        P.qkv[n * 1536 + col0 + 256] = a1;
    } else {
        for (int i = t; i < SEQ * D; i += 256) { P.x2[i] = 0.f; P.out[i] = 0.f; }
    }
    grid.sync();

    // ================= Phase B: gate (block 0) | attention (1..130) ========
    if (b == 0) {
        float* sb1 = smem + 4;    // 64
        float* sb2 = smem + 68;   // 64
        float* hid = smem + 132;  // 12
        if (t < NCH) sb1[t] = P.b1[t];
        __syncthreads();
        if (t < NCH) {
            float v = sb1[t];
            float mx = -1e30f, mn = 1e30f;
            int cle = 0, rank = 0;
            for (int j = 0; j < NCH; j++) {
                float w = sb1[j];
                mx = fmaxf(mx, w);
                mn = fminf(mn, w);
                if (w <= 0.f) cle++;
                if (w < v || (w == v && j < t)) rank++;
            }
            int middle;
            if (mx < 0.f || mn > 0.f) middle = 32;
            else if (mx <= 0.f) middle = 0;
            else middle = cle;
            float b2;
            if (rank < middle) {
                float ls = (float)middle;
                b2 = v - 1.f / (1.f + powf(ls, v));
            } else {
                float le = (float)(NCH - middle);
                b2 = v + 1.f / (1.f + powf(le, -v));
            }
            sb2[t] = b2;
        }
        __syncthreads();
        if (t < 12) {
            float s = 0.f;
            for (int j = 0; j < NCH; j++) s += sb2[j] * P.fc_w1[j * 12 + t];
            hid[t] = fmaxf(s, 0.f);
        }
        __syncthreads();
        if (t < NCH) {
            float s = 0.f;
            for (int k = 0; k < 12; k++) s += hid[k] * P.fc_w2[k * NCH + t];
            P.c[t] = 1.f / (1.f + expf(-s));
        }
    } else if (b <= 130) {
        int w = t >> 6, lane = t & 63;
        int task = (b - 1) * 4 + w;          // 0..519
        int n = task >> 3, hh = task & 7;
        float* q = smem + 4 + w * 64;        // [4,260)
        float* pp = smem + 260 + w * 66;     // [260,524)
        q[lane] = P.qkv[n * 1536 + hh * DHD + lane];
        __syncthreads();
        const float scale = 0.125f;
        for (int m = lane; m < SEQ; m += 64) {
            const float* kr = P.qkv + m * 1536 + INNER + hh * DHD;
            float s = 0.f;
#pragma unroll 8
            for (int dd = 0; dd < DHD; dd++) s += q[dd] * kr[dd];
            pp[m] = s * scale;
        }
        __syncthreads();
        float mx = -1e30f;
#pragma unroll 5
        for (int m = 0; m < SEQ; m++) mx = fmaxf(mx, pp[m]);
        __syncthreads();
        for (int m = lane; m < SEQ; m += 64) pp[m] = expf(pp[m] - mx);
        __syncthreads();
        float sum = 0.f;
#pragma unroll 5
        for (int m = 0; m < SEQ; m++) sum += pp[m];
        float rs = 1.f / sum;
        float acc = 0.f;
#pragma unroll 4
        for (int m = 0; m < SEQ; m++)
            acc += pp[m] * P.qkv[m * 1536 + 2 * INNER + hh * DHD + lane];
        P.o[n * INNER + hh * DHD + lane] = acc * rs;
    }
    grid.sync();

    // ================= Phase C: out-proj split-K + residuals ===============
    {
        int n = b >> 2, kc = b & 3;
        float* st = smem + 4;  // 128
        if (t < 128) st[t] = P.o[n * INNER + kc * 128 + t];
        __syncthreads();
        if (t < D) {
            const float* wp = P.w_out + (kc * 128) * D + t;
            float acc = 0.f;
#pragma unroll 4
            for (int i = 0; i < 128; i++) acc += st[i] * wp[i * D];
            if (kc == 0) {
                float att = (n < NCH) ? P.a[n * D + t] * P.c[n] : P.tokens[t];
                acc += P.b_out[t] + P.x[n * D + t] + att;
            }
            atomicAdd(&P.x2[n * D + t], acc);
        }
    }
    grid.sync();

    // ================= Phase D: LN2 + FF1 + GELU ===========================
    {
        int n = b >> 2, g2 = b & 3;
        const float* row = P.x2 + n * D;
        float v = (t < D) ? row[t] : 0.f;
        float mean = bsum(v, red) * (1.f / (float)D);
        float d = (t < D) ? (v - mean) : 0.f;
        float var = bsum(d * d, red) * (1.f / (float)D);
        float rinv = rsqrtf(var + 1e-5f);
        if (t < D) h[t] = d * rinv * P.ln2_g[t] + P.ln2_b[t];
        __syncthreads();
        if (t < D) {
            int col = g2 * D + t;  // 0..783
            const float* wp = P.ff_w1 + col;
            float acc = P.ff_b1[col];
#pragma unroll 4
            for (int i = 0; i < D; i++) acc += h[i] * wp[i * MLP];
            float gl = 0.5f * acc * (1.f + erff(acc * 0.70710678118f));
            P.tb[n * MLP + col] = gl;
        }
    }
    grid.sync();

    // ================= Phase E: FF2 split-K + residual =====================
    {
        int n = b >> 2, kc = b & 3;
        float* st = smem + 4;  // 196
        if (t < D) st[t] = P.tb[n * MLP + kc * D + t];
        __syncthreads();
        if (t < D) {
            const float* wp = P.ff_w2 + (kc * D) * D + t;
            float acc = 0.f;
#pragma unroll 4
            for (int i = 0; i < D; i++) acc += st[i] * wp[i * D];
            if (kc == 0) acc += P.ff_b2[t] + P.x2[n * D + t];
            atomicAdd(&P.out[n * D + t], acc);
        }
    }
}

extern "C" void kernel_launch(void* const* d_in, const int* in_sizes, int n_in,
                              void* d_out, int out_size, void* d_ws, size_t ws_size,
                              hipStream_t stream) {
    float* ws = (float*)d_ws;
    Params P;
    P.x      = (const float*)d_in[0];
    P.tokens = (const float*)d_in[1];
    P.x_pe   = (const float*)d_in[2];
    P.conv_k = (const float*)d_in[3];
    P.bn_g   = (const float*)d_in[4];
    P.bn_b   = (const float*)d_in[5];
    P.bn_rm  = (const float*)d_in[6];
    P.bn_rv  = (const float*)d_in[7];
    P.fc_w1  = (const float*)d_in[8];
    P.fc_w2  = (const float*)d_in[9];
    P.ln1_g  = (const float*)d_in[10];
    P.ln1_b  = (const float*)d_in[11];
    P.ln2_g  = (const float*)d_in[12];
    P.ln2_b  = (const float*)d_in[13];
    P.w_qkv  = (const float*)d_in[14];
    P.w_out  = (const float*)d_in[15];
    P.b_out  = (const float*)d_in[16];
    P.ff_w1  = (const float*)d_in[17];
    P.ff_b1  = (const float*)d_in[18];
    P.ff_w2  = (const float*)d_in[19];
    P.ff_b2  = (const float*)d_in[20];
    P.a   = ws;             // 12544
    P.b1  = ws + 12544;     // 64
    P.c   = ws + 12608;     // 64
    P.qkv = ws + 12672;     // 99840
    P.o   = ws + 112512;    // 33280
    P.x2  = ws + 145792;    // 12740
    P.tb  = ws + 158532;    // 50960
    P.out = (float*)d_out;

    void* args[] = { &P };
    hipLaunchCooperativeKernel((void*)k_fused, dim3(GRID), dim3(256), args, 0, stream);
}

// Round 4
// 130.684 us; speedup vs baseline: 2.3722x; 2.3722x over previous
//
#include <hip/hip_runtime.h>
#include <math.h>

#define D 196
#define NCH 64
#define NH 8
#define DHD 64
#define INNER 512
#define MLP 784
#define SEQ 65

__device__ __forceinline__ float bsum(float v, float* red) {
    for (int off = 32; off > 0; off >>= 1) v += __shfl_down(v, off, 64);
    int lane = threadIdx.x & 63, wid = threadIdx.x >> 6;
    if (lane == 0) red[wid] = v;
    __syncthreads();
    float s = red[0] + red[1] + red[2] + red[3];
    __syncthreads();
    return s;
}

// ===== K1: conv+mean (blocks 0..63) | LN1+QKV split-K (64..843) | zero (844) =====
__global__ void __launch_bounds__(256) k1(const float* __restrict__ x_pe,
        const float* __restrict__ conv_k, const float* __restrict__ bn_g,
        const float* __restrict__ bn_b, const float* __restrict__ bn_rm,
        const float* __restrict__ bn_rv, const float* __restrict__ x,
        const float* __restrict__ ln1_g, const float* __restrict__ ln1_b,
        const float* __restrict__ w_qkv,
        float* __restrict__ a, float* __restrict__ b1, float* __restrict__ qkv,
        float* __restrict__ x2, float* __restrict__ out) {
    __shared__ float red[4];
    __shared__ float h[D];
    __shared__ float ps[256];
    int b = blockIdx.x, t = threadIdx.x;
    if (b < NCH) {
        const float* row = x_pe + b * D;
        float val = 0.f;
        if (t < D) {
            float km0 = conv_k[3], km1 = conv_k[4], km2 = conv_k[5];
            float inv = rsqrtf(bn_rv[0] + 1e-5f);
            float l = (t > 0) ? row[t - 1] : 0.f;
            float m = row[t];
            float r = (t < D - 1) ? row[t + 1] : 0.f;
            float conv = km0 * l + km1 * m + km2 * r;
            float bn = (conv - bn_rm[0]) * inv * bn_g[0] + bn_b[0];
            val = fmaxf(bn, 0.f);
            a[b * D + t] = val;
        }
        float tot = bsum(val, red);
        if (t == 0) b1[b] = tot * (1.f / (float)D);
    } else if (b < 844) {
        int qb = b - NCH;          // 0..779
        int n = qb / 12, cg = qb % 12;
        const float* row = x + n * D;
        float v = (t < D) ? row[t] : 0.f;
        float mean = bsum(v, red) * (1.f / (float)D);
        float d = (t < D) ? (v - mean) : 0.f;
        float var = bsum(d * d, red) * (1.f / (float)D);
        float rinv = rsqrtf(var + 1e-5f);
        if (t < D) h[t] = d * rinv * ln1_g[t] + ln1_b[t];
        __syncthreads();
        int half = t >> 7, lt = t & 127;
        int col = cg * 128 + lt;
        const float* wp = w_qkv + (half * 98) * 1536 + col;
        const float* hp = h + half * 98;
        float acc = 0.f;
#pragma unroll 14
        for (int i = 0; i < 98; i++) acc += hp[i] * wp[i * 1536];
        ps[t] = acc;
        __syncthreads();
        if (t < 128) qkv[n * 1536 + cg * 128 + t] = ps[t] + ps[t + 128];
    } else {
        for (int i = t; i < SEQ * D; i += 256) { x2[i] = 0.f; out[i] = 0.f; }
    }
}

// ===== K2: gate (block 0) | attention (blocks 1..130, one wave per (n,h)) =====
__global__ void __launch_bounds__(256) k2(const float* __restrict__ b1,
        const float* __restrict__ fc_w1, const float* __restrict__ fc_w2,
        const float* __restrict__ qkv, float* __restrict__ c, float* __restrict__ o) {
    __shared__ float smem[544];
    int b = blockIdx.x, t = threadIdx.x;
    if (b == 0) {
        float* sb1 = smem;        // 64
        float* sb2 = smem + 64;   // 64
        float* hid = smem + 128;  // 12
        if (t < NCH) sb1[t] = b1[t];
        __syncthreads();
        if (t < NCH) {
            float v = sb1[t];
            float mx = -1e30f, mn = 1e30f;
            int cle = 0, rank = 0;
            for (int j = 0; j < NCH; j++) {
                float w = sb1[j];
                mx = fmaxf(mx, w);
                mn = fminf(mn, w);
                if (w <= 0.f) cle++;
                if (w < v || (w == v && j < t)) rank++;
            }
            int middle;
            if (mx < 0.f || mn > 0.f) middle = 32;
            else if (mx <= 0.f) middle = 0;
            else middle = cle;
            float b2;
            if (rank < middle) {
                float ls = (float)middle;
                b2 = v - 1.f / (1.f + powf(ls, v));
            } else {
                float le = (float)(NCH - middle);
                b2 = v + 1.f / (1.f + powf(le, -v));
            }
            sb2[t] = b2;
        }
        __syncthreads();
        if (t < 12) {
            float s = 0.f;
            for (int j = 0; j < NCH; j++) s += sb2[j] * fc_w1[j * 12 + t];
            hid[t] = fmaxf(s, 0.f);
        }
        __syncthreads();
        if (t < NCH) {
            float s = 0.f;
            for (int k = 0; k < 12; k++) s += hid[k] * fc_w2[k * NCH + t];
            c[t] = 1.f / (1.f + expf(-s));
        }
    } else {
        int w = t >> 6, lane = t & 63;
        int task = (b - 1) * 4 + w;        // 0..519
        int n = task >> 3, hh = task & 7;
        float* q = smem + w * 64;          // [0,256)
        float* pp = smem + 256 + w * 66;   // [256,520)
        q[lane] = qkv[n * 1536 + hh * DHD + lane];
        __syncthreads();
        const float4* q4 = (const float4*)q;
        const float scale = 0.125f;
        for (int m = lane; m < SEQ; m += 64) {
            const float4* kr = (const float4*)(qkv + m * 1536 + INNER + hh * DHD);
            float s = 0.f;
#pragma unroll
            for (int i = 0; i < 16; i++) {
                float4 kv = kr[i];
                float4 qv = q4[i];
                s += qv.x * kv.x + qv.y * kv.y + qv.z * kv.z + qv.w * kv.w;
            }
            pp[m] = s * scale;
        }
        __syncthreads();
        float mx = -1e30f;
#pragma unroll 5
        for (int m = 0; m < SEQ; m++) mx = fmaxf(mx, pp[m]);
        __syncthreads();
        for (int m = lane; m < SEQ; m += 64) pp[m] = expf(pp[m] - mx);
        __syncthreads();
        float sum = 0.f;
#pragma unroll 5
        for (int m = 0; m < SEQ; m++) sum += pp[m];
        float rs = 1.f / sum;
        float acc = 0.f;
#pragma unroll 8
        for (int m = 0; m < SEQ; m++)
            acc += pp[m] * qkv[m * 1536 + 2 * INNER + hh * DHD + lane];
        o[n * INNER + hh * DHD + lane] = acc * rs;
    }
}

// ===== K3: out-proj split-K×4 + residuals, atomicAdd into x2 =====
__global__ void __launch_bounds__(256) k3(const float* __restrict__ o,
        const float* __restrict__ w_out, const float* __restrict__ b_out,
        const float* __restrict__ x, const float* __restrict__ a,
        const float* __restrict__ c, const float* __restrict__ tokens,
        float* __restrict__ x2) {
    __shared__ float st[128];
    int n = blockIdx.x, kc = blockIdx.y, t = threadIdx.x;
    if (t < 128) st[t] = o[n * INNER + kc * 128 + t];
    __syncthreads();
    if (t < D) {
        const float* wp = w_out + (kc * 128) * D + t;
        float acc = 0.f;
#pragma unroll 16
        for (int i = 0; i < 128; i++) acc += st[i] * wp[i * D];
        if (kc == 0) {
            float att = (n < NCH) ? a[n * D + t] * c[n] : tokens[t];
            acc += b_out[t] + x[n * D + t] + att;
        }
        atomicAdd(&x2[n * D + t], acc);
    }
}

// ===== K4: LN2 + FF1 split-K×2 + GELU, grid (65,8) =====
__global__ void __launch_bounds__(256) k4(const float* __restrict__ x2,
        const float* __restrict__ ln2_g, const float* __restrict__ ln2_b,
        const float* __restrict__ ff_w1, const float* __restrict__ ff_b1,
        float* __restrict__ tb) {
    __shared__ float red[4];
    __shared__ float h[D];
    __shared__ float ps[256];
    int n = blockIdx.x, cg = blockIdx.y, t = threadIdx.x;
    const float* row = x2 + n * D;
    float v = (t < D) ? row[t] : 0.f;
    float mean = bsum(v, red) * (1.f / (float)D);
    float d = (t < D) ? (v - mean) : 0.f;
    float var = bsum(d * d, red) * (1.f / (float)D);
    float rinv = rsqrtf(var + 1e-5f);
    if (t < D) h[t] = d * rinv * ln2_g[t] + ln2_b[t];
    __syncthreads();
    int half = t >> 7, lt = t & 127;
    float acc = 0.f;
    if (lt < 98) {
        int col = cg * 98 + lt;
        const float* wp = ff_w1 + (half * 98) * MLP + col;
        const float* hp = h + half * 98;
        acc = (half == 0) ? ff_b1[col] : 0.f;
#pragma unroll 14
        for (int i = 0; i < 98; i++) acc += hp[i] * wp[i * MLP];
    }
    ps[t] = acc;
    __syncthreads();
    if (t < 98) {
        float s = ps[t] + ps[t + 128];
        float gl = 0.5f * s * (1.f + erff(s * 0.70710678118f));
        tb[n * MLP + cg * 98 + t] = gl;
    }
}

// ===== K5: FF2 split-K×8 + residual, atomicAdd into out, grid (65,8) =====
__global__ void __launch_bounds__(256) k5(const float* __restrict__ tb,
        const float* __restrict__ ff_w2, const float* __restrict__ ff_b2,
        const float* __restrict__ x2, float* __restrict__ out) {
    __shared__ float st[98];
    int n = blockIdx.x, kc = blockIdx.y, t = threadIdx.x;
    if (t < 98) st[t] = tb[n * MLP + kc * 98 + t];
    __syncthreads();
    if (t < D) {
        const float* wp = ff_w2 + (kc * 98) * D + t;
        float acc = 0.f;
#pragma unroll 14
        for (int i = 0; i < 98; i++) acc += st[i] * wp[i * D];
        if (kc == 0) acc += ff_b2[t] + x2[n * D + t];
        atomicAdd(&out[n * D + t], acc);
    }
}

extern "C" void kernel_launch(void* const* d_in, const int* in_sizes, int n_in,
                              void* d_out, int out_size, void* d_ws, size_t ws_size,
                              hipStream_t stream) {
    const float* x      = (const float*)d_in[0];
    const float* tokens = (const float*)d_in[1];
    const float* x_pe   = (const float*)d_in[2];
    const float* conv_k = (const float*)d_in[3];
    const float* bn_g   = (const float*)d_in[4];
    const float* bn_b   = (const float*)d_in[5];
    const float* bn_rm  = (const float*)d_in[6];
    const float* bn_rv  = (const float*)d_in[7];
    const float* fc_w1  = (const float*)d_in[8];
    const float* fc_w2  = (const float*)d_in[9];
    const float* ln1_g  = (const float*)d_in[10];
    const float* ln1_b  = (const float*)d_in[11];
    const float* ln2_g  = (const float*)d_in[12];
    const float* ln2_b  = (const float*)d_in[13];
    const float* w_qkv  = (const float*)d_in[14];
    const float* w_out  = (const float*)d_in[15];
    const float* b_out  = (const float*)d_in[16];
    const float* ff_w1  = (const float*)d_in[17];
    const float* ff_b1  = (const float*)d_in[18];
    const float* ff_w2  = (const float*)d_in[19];
    const float* ff_b2  = (const float*)d_in[20];
    float* out = (float*)d_out;

    float* ws = (float*)d_ws;
    float* a    = ws;             // 12544
    float* b1   = ws + 12544;     // 64
    float* cc   = ws + 12608;     // 64
    float* qkv  = ws + 12672;     // 99840
    float* o    = ws + 112512;    // 33280
    float* x2   = ws + 145792;    // 12740
    float* tb   = ws + 158532;    // 50960

    k1<<<845, 256, 0, stream>>>(x_pe, conv_k, bn_g, bn_b, bn_rm, bn_rv,
                                x, ln1_g, ln1_b, w_qkv, a, b1, qkv, x2, out);
    k2<<<131, 256, 0, stream>>>(b1, fc_w1, fc_w2, qkv, cc, o);
    k3<<<dim3(SEQ, 4), 256, 0, stream>>>(o, w_out, b_out, x, a, cc, tokens, x2);
    k4<<<dim3(SEQ, 8), 256, 0, stream>>>(x2, ln2_g, ln2_b, ff_w1, ff_b1, tb);
    k5<<<dim3(SEQ, 8), 256, 0, stream>>>(tb, ff_w2, ff_b2, x2, out);
}

// Round 5
// 130.119 us; speedup vs baseline: 2.3825x; 1.0043x over previous
//
#include <hip/hip_runtime.h>
#include <math.h>

#define D 196
#define NCH 64
#define NH 8
#define DHD 64
#define INNER 512
#define MLP 784
#define SEQ 65

__device__ __forceinline__ float bsum(float v, float* red) {
    for (int off = 32; off > 0; off >>= 1) v += __shfl_down(v, off, 64);
    int lane = threadIdx.x & 63, wid = threadIdx.x >> 6;
    if (lane == 0) red[wid] = v;
    __syncthreads();
    float s = red[0] + red[1] + red[2] + red[3];
    __syncthreads();
    return s;
}

// ===== K1: conv+mean+zero (blocks 0..63) | LN1+QKV splitK4 x colpair (64..843) =====
__global__ void __launch_bounds__(256) k1(const float* __restrict__ x_pe,
        const float* __restrict__ conv_k, const float* __restrict__ bn_g,
        const float* __restrict__ bn_b, const float* __restrict__ bn_rm,
        const float* __restrict__ bn_rv, const float* __restrict__ x,
        const float* __restrict__ ln1_g, const float* __restrict__ ln1_b,
        const float* __restrict__ w_qkv,
        float* __restrict__ a, float* __restrict__ b1, float* __restrict__ qkv,
        float* __restrict__ out) {
    __shared__ float red[4];
    __shared__ float h[D];
    __shared__ float ps[512];
    int b = blockIdx.x, t = threadIdx.x;
    if (b < NCH) {
        // zero a slice of out (12740 total; 64 blocks x 200)
        int zi = b * 200 + t;
        if (t < 200 && zi < SEQ * D) out[zi] = 0.f;
        const float* row = x_pe + b * D;
        float val = 0.f;
        if (t < D) {
            float km0 = conv_k[3], km1 = conv_k[4], km2 = conv_k[5];
            float inv = rsqrtf(bn_rv[0] + 1e-5f);
            float l = (t > 0) ? row[t - 1] : 0.f;
            float m = row[t];
            float r = (t < D - 1) ? row[t + 1] : 0.f;
            float conv = km0 * l + km1 * m + km2 * r;
            float bn = (conv - bn_rm[0]) * inv * bn_g[0] + bn_b[0];
            val = fmaxf(bn, 0.f);
            a[b * D + t] = val;
        }
        float tot = bsum(val, red);
        if (t == 0) b1[b] = tot * (1.f / (float)D);
    } else {
        int qb = b - NCH;          // 0..779
        int n = qb / 12, cg = qb % 12;
        const float* row = x + n * D;
        float v = (t < D) ? row[t] : 0.f;
        float mean = bsum(v, red) * (1.f / (float)D);
        float d = (t < D) ? (v - mean) : 0.f;
        float var = bsum(d * d, red) * (1.f / (float)D);
        float rinv = rsqrtf(var + 1e-5f);
        if (t < D) h[t] = d * rinv * ln1_g[t] + ln1_b[t];
        __syncthreads();
        int qq = t >> 6, lt = t & 63;        // qq: K quarter, lt: col pair
        int c0 = cg * 128 + lt * 2;
        const float* wp = w_qkv + (qq * 49) * 1536 + c0;
        const float* hp = h + qq * 49;
        float a0 = 0.f, a1 = 0.f;
#pragma unroll
        for (int i = 0; i < 49; i++) {
            float2 w2 = *(const float2*)(wp + i * 1536);
            float hv = hp[i];
            a0 += hv * w2.x;
            a1 += hv * w2.y;
        }
        ps[qq * 128 + lt * 2] = a0;
        ps[qq * 128 + lt * 2 + 1] = a1;
        __syncthreads();
        if (t < 64) {
            float s0 = ps[t * 2] + ps[128 + t * 2] + ps[256 + t * 2] + ps[384 + t * 2];
            float s1 = ps[t * 2 + 1] + ps[129 + t * 2] + ps[257 + t * 2] + ps[385 + t * 2];
            float2 o2 = make_float2(s0, s1);
            *(float2*)(qkv + n * 1536 + cg * 128 + t * 2) = o2;
        }
    }
}

// ===== K2: attention+out-proj (blocks 0..64, 512 thr) | gate (block 65) =====
__global__ void __launch_bounds__(512) k2(const float* __restrict__ b1,
        const float* __restrict__ fc_w1, const float* __restrict__ fc_w2,
        const float* __restrict__ qkv, const float* __restrict__ w_out,
        const float* __restrict__ b_out, const float* __restrict__ x,
        float* __restrict__ c, float* __restrict__ x2) {
    int b = blockIdx.x, t = threadIdx.x;
    if (b == SEQ) {
        __shared__ float sb1[NCH];
        __shared__ float sb2[NCH];
        __shared__ float hid[12];
        if (t < NCH) sb1[t] = b1[t];
        __syncthreads();
        if (t < NCH) {
            float v = sb1[t];
            float mx = -1e30f, mn = 1e30f;
            int cle = 0, rank = 0;
            for (int j = 0; j < NCH; j++) {
                float w = sb1[j];
                mx = fmaxf(mx, w);
                mn = fminf(mn, w);
                if (w <= 0.f) cle++;
                if (w < v || (w == v && j < t)) rank++;
            }
            int middle;
            if (mx < 0.f || mn > 0.f) middle = 32;
            else if (mx <= 0.f) middle = 0;
            else middle = cle;
            float b2;
            if (rank < middle) {
                float ls = (float)middle;
                b2 = v - 1.f / (1.f + powf(ls, v));
            } else {
                float le = (float)(NCH - middle);
                b2 = v + 1.f / (1.f + powf(le, -v));
            }
            sb2[t] = b2;
        }
        __syncthreads();
        if (t < 12) {
            float s = 0.f;
            for (int j = 0; j < NCH; j++) s += sb2[j] * fc_w1[j * 12 + t];
            hid[t] = fmaxf(s, 0.f);
        }
        __syncthreads();
        if (t < NCH) {
            float s = 0.f;
            for (int k = 0; k < 12; k++) s += hid[k] * fc_w2[k * NCH + t];
            c[t] = 1.f / (1.f + expf(-s));
        }
        return;
    }
    // attention: 8 waves = 8 heads of row n = b
    __shared__ float sq[512];
    __shared__ float pp[8 * 80];
    __shared__ float so[512];
    __shared__ float ps[784];
    int n = b;
    int w = t >> 6, L = t & 63;   // head, lane
    sq[t] = qkv[n * 1536 + t];    // all 8 heads' q
    __syncthreads();
    const float scale = 0.125f;
    // score for key row m = L (uncoalesced but 16 loads in flight, L2-resident)
    const float4* kr = (const float4*)(qkv + L * 1536 + INNER + w * DHD);
    const float4* q4 = (const float4*)(sq + w * DHD);
    float s = 0.f;
#pragma unroll
    for (int i = 0; i < 16; i++) {
        float4 kv = kr[i];
        float4 qv = q4[i];
        s += qv.x * kv.x + qv.y * kv.y + qv.z * kv.z + qv.w * kv.w;
    }
    float sL = s * scale;
    // score for key row m=64, distributed across lanes
    float t64 = sq[w * DHD + L] * qkv[64 * 1536 + INNER + w * DHD + L];
#pragma unroll
    for (int off = 1; off < 64; off <<= 1) t64 += __shfl_xor(t64, off, 64);
    float s64 = t64 * scale;
    // softmax over 65 scores
    float mx = sL;
#pragma unroll
    for (int off = 1; off < 64; off <<= 1) mx = fmaxf(mx, __shfl_xor(mx, off, 64));
    mx = fmaxf(mx, s64);
    float e = expf(sL - mx);
    float e64 = expf(s64 - mx);
    float esum = e;
#pragma unroll
    for (int off = 1; off < 64; off <<= 1) esum += __shfl_xor(esum, off, 64);
    esum += e64;
    float rs = 1.f / esum;
    pp[w * 80 + L] = e;
    if (L == 0) pp[w * 80 + 64] = e64;
    __syncthreads();
    // PV: lane L accumulates output dim L of head w
    float acc = 0.f;
#pragma unroll 13
    for (int m = 0; m < SEQ; m++)
        acc += pp[w * 80 + m] * qkv[m * 1536 + 2 * INNER + w * DHD + L];
    so[w * DHD + L] = acc * rs;
    __syncthreads();
    // out-projection: 98 col-pairs x 4 K-quarters = 392 active threads
    if (t < 392) {
        int qq = t / 98, p = t - qq * 98;   // K quarter, col pair
        const float* wp = w_out + (qq * 128) * D + 2 * p;
        const float* op = so + qq * 128;
        float a0 = 0.f, a1 = 0.f;
#pragma unroll 16
        for (int i = 0; i < 128; i++) {
            float2 w2 = *(const float2*)(wp + i * D);
            float ov = op[i];
            a0 += ov * w2.x;
            a1 += ov * w2.y;
        }
        ps[qq * 196 + 2 * p] = a0;
        ps[qq * 196 + 2 * p + 1] = a1;
    }
    __syncthreads();
    if (t < 98) {
        float s0 = ps[2 * t] + ps[196 + 2 * t] + ps[392 + 2 * t] + ps[588 + 2 * t];
        float s1 = ps[2 * t + 1] + ps[197 + 2 * t] + ps[393 + 2 * t] + ps[589 + 2 * t];
        // x2' = attn_proj + x + b_out   (x_att added downstream)
        float2 xr = *(const float2*)(x + n * D + 2 * t);
        float2 br = *(const float2*)(b_out + 2 * t);
        float2 o2 = make_float2(s0 + xr.x + br.x, s1 + xr.y + br.y);
        *(float2*)(x2 + n * D + 2 * t) = o2;
    }
}

// ===== K3: LN2(+x_att) + FF1 splitK4 x colpair + GELU, grid (65,8) =====
__global__ void __launch_bounds__(256) k3(const float* __restrict__ x2,
        const float* __restrict__ a, const float* __restrict__ c,
        const float* __restrict__ tokens,
        const float* __restrict__ ln2_g, const float* __restrict__ ln2_b,
        const float* __restrict__ ff_w1, const float* __restrict__ ff_b1,
        float* __restrict__ tb) {
    __shared__ float red[4];
    __shared__ float h[D];
    __shared__ float ps[392];
    int n = blockIdx.x, cg = blockIdx.y, t = threadIdx.x;
    float v = 0.f;
    if (t < D) {
        float att = (n < NCH) ? a[n * D + t] * c[n] : tokens[t];
        v = x2[n * D + t] + att;
    }
    float mean = bsum(v, red) * (1.f / (float)D);
    float d = (t < D) ? (v - mean) : 0.f;
    float var = bsum(d * d, red) * (1.f / (float)D);
    float rinv = rsqrtf(var + 1e-5f);
    if (t < D) h[t] = d * rinv * ln2_g[t] + ln2_b[t];
    __syncthreads();
    if (t < D) {
        int qq = t / 49, p = t - qq * 49;    // K quarter, col pair
        int c0 = cg * 98 + 2 * p;
        const float* wp = ff_w1 + (qq * 49) * MLP + c0;
        const float* hp = h + qq * 49;
        float a0 = 0.f, a1 = 0.f;
#pragma unroll
        for (int i = 0; i < 49; i++) {
            float2 w2 = *(const float2*)(wp + i * MLP);
            float hv = hp[i];
            a0 += hv * w2.x;
            a1 += hv * w2.y;
        }
        if (qq == 0) { a0 += ff_b1[c0]; a1 += ff_b1[c0 + 1]; }
        ps[qq * 98 + 2 * p] = a0;
        ps[qq * 98 + 2 * p + 1] = a1;
    }
    __syncthreads();
    if (t < 49) {
        float s0 = ps[2 * t] + ps[98 + 2 * t] + ps[196 + 2 * t] + ps[294 + 2 * t];
        float s1 = ps[2 * t + 1] + ps[99 + 2 * t] + ps[197 + 2 * t] + ps[295 + 2 * t];
        float g0 = 0.5f * s0 * (1.f + erff(s0 * 0.70710678118f));
        float g1 = 0.5f * s1 * (1.f + erff(s1 * 0.70710678118f));
        *(float2*)(tb + n * MLP + cg * 98 + 2 * t) = make_float2(g0, g1);
    }
}

// ===== K4: FF2 splitK8 x colpair + residual, atomicAdd into out, grid (65,8) =====
__global__ void __launch_bounds__(256) k4(const float* __restrict__ tb,
        const float* __restrict__ ff_w2, const float* __restrict__ ff_b2,
        const float* __restrict__ x2, const float* __restrict__ a,
        const float* __restrict__ c, const float* __restrict__ tokens,
        float* __restrict__ out) {
    __shared__ float st[98];
    __shared__ float ps[392];
    int n = blockIdx.x, kc = blockIdx.y, t = threadIdx.x;
    if (t < 98) st[t] = tb[n * MLP + kc * 98 + t];
    __syncthreads();
    if (t < D) {
        int hh = t / 98, p = t - hh * 98;    // K half, col pair
        const float* wp = ff_w2 + (kc * 98 + hh * 49) * D + 2 * p;
        const float* sp = st + hh * 49;
        float a0 = 0.f, a1 = 0.f;
#pragma unroll
        for (int i = 0; i < 49; i++) {
            float2 w2 = *(const float2*)(wp + i * D);
            float sv = sp[i];
            a0 += sv * w2.x;
            a1 += sv * w2.y;
        }
        ps[hh * 196 + 2 * p] = a0;
        ps[hh * 196 + 2 * p + 1] = a1;
    }
    __syncthreads();
    if (t < 98) {
        float s0 = ps[2 * t] + ps[196 + 2 * t];
        float s1 = ps[2 * t + 1] + ps[197 + 2 * t];
        if (kc == 0) {
            int c0 = 2 * t;
            float att0 = (n < NCH) ? a[n * D + c0] * c[n] : tokens[c0];
            float att1 = (n < NCH) ? a[n * D + c0 + 1] * c[n] : tokens[c0 + 1];
            s0 += ff_b2[c0] + x2[n * D + c0] + att0;
            s1 += ff_b2[c0 + 1] + x2[n * D + c0 + 1] + att1;
        }
        atomicAdd(&out[n * D + 2 * t], s0);
        atomicAdd(&out[n * D + 2 * t + 1], s1);
    }
}

extern "C" void kernel_launch(void* const* d_in, const int* in_sizes, int n_in,
                              void* d_out, int out_size, void* d_ws, size_t ws_size,
                              hipStream_t stream) {
    const float* x      = (const float*)d_in[0];
    const float* tokens = (const float*)d_in[1];
    const float* x_pe   = (const float*)d_in[2];
    const float* conv_k = (const float*)d_in[3];
    const float* bn_g   = (const float*)d_in[4];
    const float* bn_b   = (const float*)d_in[5];
    const float* bn_rm  = (const float*)d_in[6];
    const float* bn_rv  = (const float*)d_in[7];
    const float* fc_w1  = (const float*)d_in[8];
    const float* fc_w2  = (const float*)d_in[9];
    const float* ln1_g  = (const float*)d_in[10];
    const float* ln1_b  = (const float*)d_in[11];
    const float* ln2_g  = (const float*)d_in[12];
    const float* ln2_b  = (const float*)d_in[13];
    const float* w_qkv  = (const float*)d_in[14];
    const float* w_out  = (const float*)d_in[15];
    const float* b_out  = (const float*)d_in[16];
    const float* ff_w1  = (const float*)d_in[17];
    const float* ff_b1  = (const float*)d_in[18];
    const float* ff_w2  = (const float*)d_in[19];
    const float* ff_b2  = (const float*)d_in[20];
    float* out = (float*)d_out;

    float* ws = (float*)d_ws;
    float* a    = ws;             // 12544
    float* b1   = ws + 12544;     // 64
    float* cc   = ws + 12608;     // 64
    float* qkv  = ws + 12672;     // 99840
    float* x2   = ws + 112512;    // 12740
    float* tb   = ws + 125252;    // 50960

    k1<<<844, 256, 0, stream>>>(x_pe, conv_k, bn_g, bn_b, bn_rm, bn_rv,
                                x, ln1_g, ln1_b, w_qkv, a, b1, qkv, out);
    k2<<<SEQ + 1, 512, 0, stream>>>(b1, fc_w1, fc_w2, qkv, w_out, b_out, x, cc, x2);
    k3<<<dim3(SEQ, 8), 256, 0, stream>>>(x2, a, cc, tokens, ln2_g, ln2_b,
                                         ff_w1, ff_b1, tb);
    k4<<<dim3(SEQ, 8), 256, 0, stream>>>(tb, ff_w2, ff_b2, x2, a, cc, tokens, out);
}